// Round 8
// baseline (207.668 us; speedup 1.0000x reference)
//
#include <hip/hip_runtime.h>
#include <hip/hip_bf16.h>

#define DD 128
#define BSH 8          // 256 nodes per bucket (CSR build)
#define CHUNK 4096     // edges per partition block

typedef __attribute__((ext_vector_type(8))) short short8v;
typedef __attribute__((ext_vector_type(4))) float f32x4;

static __device__ __forceinline__ ushort f2bf(float f) {
    __hip_bfloat16 b = __float2bfloat16(f);
    return *reinterpret_cast<ushort*>(&b);
}

// ---------------- CSR build: chunked radix partition ----------------

__global__ __launch_bounds__(256) void k_hist(const int* __restrict__ ei,
                                              int* __restrict__ hist, int E, int NB) {
    __shared__ int lh[256];
    int t = threadIdx.x;
    lh[t] = 0;
    __syncthreads();
    int e0 = blockIdx.x * CHUNK;
    int e1 = min(e0 + CHUNK, E);
    for (int e = e0 + t; e < e1; e += 256)
        atomicAdd(&lh[ei[E + e] >> BSH], 1);
    __syncthreads();
    if (t < NB) hist[blockIdx.x * NB + t] = lh[t];
}

__global__ __launch_bounds__(1024) void k_hscan(int* __restrict__ hist,
                                                int* __restrict__ bbase,
                                                int nblk, int NB, int E) {
    __shared__ int part[4][256];
    __shared__ int s[256];
    int t = threadIdx.x;
    int b = t & 255, g = t >> 8;
    int q = (nblk + 3) >> 2;
    int lo = g * q, hi = min(lo + q, nblk);
    int sum = 0;
    if (b < NB)
        for (int blk = lo; blk < hi; ++blk) sum += hist[blk * NB + b];
    part[g][b] = sum;
    __syncthreads();
    if (g == 0) s[b] = part[0][b] + part[1][b] + part[2][b] + part[3][b];
    __syncthreads();
    for (int off = 1; off < 256; off <<= 1) {
        int v = 0;
        if (g == 0 && b >= off) v = s[b - off];
        __syncthreads();
        if (g == 0) s[b] += v;
        __syncthreads();
    }
    int base = (b == 0) ? 0 : s[b - 1];
    if (g == 0 && b < NB) bbase[b] = base;
    if (t == 0) bbase[NB] = E;
    int run = base;
    for (int gg = 0; gg < g; ++gg) run += part[gg][b];
    if (b < NB)
        for (int blk = lo; blk < hi; ++blk) {
            int tmp = hist[blk * NB + b];
            hist[blk * NB + b] = run;
            run += tmp;
        }
}

__global__ __launch_bounds__(256) void k_scatter(const int* __restrict__ ei,
                                                 const int* __restrict__ hist,
                                                 uint2* __restrict__ pairs, int E, int NB) {
    __shared__ int lofs[256];
    __shared__ int lh[256];
    int t = threadIdx.x;
    int blk = blockIdx.x;
    lh[t] = 0;
    if (t < NB) lofs[t] = hist[blk * NB + t];
    __syncthreads();
    int e0 = blk * CHUNK, e1 = min(e0 + CHUNK, E);
    for (int e = e0 + t; e < e1; e += 256) {
        int sN = ei[e];
        int d = ei[E + e];
        int b = d >> BSH;
        int lp = atomicAdd(&lh[b], 1);
        pairs[lofs[b] + lp] = make_uint2((uint)sN, (uint)d);
    }
}

__global__ __launch_bounds__(256) void k_cntb(const uint2* __restrict__ pairs,
                                              const int* __restrict__ bbase,
                                              int* __restrict__ cnt, int n) {
    __shared__ int lc[256];
    int t = threadIdx.x;
    int b = blockIdx.x;
    lc[t] = 0;
    __syncthreads();
    int node0 = b << BSH;
    int r0 = bbase[b], r1 = bbase[b + 1];
    for (int i = r0 + t; i < r1; i += 256)
        atomicAdd(&lc[(int)pairs[i].y - node0], 1);
    __syncthreads();
    int node = node0 + t;
    if (node < n) cnt[node] = lc[t];
}

__global__ __launch_bounds__(256) void k_scan1(const int* __restrict__ cnt,
                                               int* __restrict__ incl,
                                               int* __restrict__ bsum, int n) {
    __shared__ int s[256];
    int t = threadIdx.x;
    int i = blockIdx.x * 256 + t;
    int v = (i < n) ? cnt[i] : 0;
    s[t] = v;
    __syncthreads();
#pragma unroll
    for (int off = 1; off < 256; off <<= 1) {
        int u = (t >= off) ? s[t - off] : 0;
        __syncthreads();
        s[t] += u;
        __syncthreads();
    }
    if (i < n) incl[i] = s[t];
    if (t == 255) bsum[blockIdx.x] = s[255];
}

__global__ __launch_bounds__(256) void k_scan2(int* __restrict__ bsum, int nb) {
    __shared__ int s[256];
    int t = threadIdx.x;
    s[t] = (t < nb) ? bsum[t] : 0;
    __syncthreads();
#pragma unroll
    for (int off = 1; off < 256; off <<= 1) {
        int u = (t >= off) ? s[t - off] : 0;
        __syncthreads();
        s[t] += u;
        __syncthreads();
    }
    if (t < nb) bsum[t] = (t == 0) ? 0 : s[t - 1];
}

__global__ __launch_bounds__(256) void k_scan3(const int* __restrict__ cnt,
                                               const int* __restrict__ incl,
                                               const int* __restrict__ bsum,
                                               int* __restrict__ rowptr,
                                               int n, int E) {
    int i = blockIdx.x * 256 + threadIdx.x;
    if (i < n) rowptr[i] = bsum[blockIdx.x] + incl[i] - cnt[i];
    if (i == 0) rowptr[n] = E;
}

__global__ __launch_bounds__(256) void k_fill3(const uint2* __restrict__ pairs,
                                               const int* __restrict__ bbase,
                                               const int* __restrict__ rowptr,
                                               int* __restrict__ eidx, int n) {
    __shared__ int cur[256];
    int t = threadIdx.x;
    int b = blockIdx.x;
    int node0 = b << BSH;
    int node = node0 + t;
    cur[t] = (node < n) ? rowptr[node] : 0;
    __syncthreads();
    int r0 = bbase[b], r1 = bbase[b + 1];
    for (int i = r0 + t; i < r1; i += 256) {
        uint2 pr = pairs[i];
        int p = atomicAdd(&cur[(int)pr.y - node0], 1);
        eidx[p] = (int)pr.x;
    }
}

// ---------------- fp32 -> bf16 cast ----------------

__global__ __launch_bounds__(256) void k_cast(const float* __restrict__ x,
                                              ushort* __restrict__ xbf, int n4) {
    int i = blockIdx.x * blockDim.x + threadIdx.x;
    if (i >= n4) return;
    float4 v = reinterpret_cast<const float4*>(x)[i];
    ushort4 o;
    o.x = f2bf(v.x); o.y = f2bf(v.y); o.z = f2bf(v.z); o.w = f2bf(v.w);
    reinterpret_cast<ushort4*>(xbf)[i] = o;
}

// ---------------- weight prep: Wt[n][k] = bf16( k<128 ? Wl[k][n] : Wr[k-128][n] ) ----

__global__ __launch_bounds__(256) void k_prepw(const float* __restrict__ Wl,
                                               const float* __restrict__ Wr,
                                               ushort* __restrict__ Wt) {
    int idx = blockIdx.x * 256 + threadIdx.x;   // 128*256 = 32768
    int nn = idx >> 8, k = idx & 255;
    float v = (k < 128) ? Wl[k * 128 + nn] : Wr[(k - 128) * 128 + nn];
    Wt[nn * 256 + k] = f2bf(v);
}

// ---------------- fused SAGE layer: mean-agg (LDS tile) + MFMA GEMM ----------------
// Block = 128 nodes, 512 threads (8 waves).
// Phase B: wave wv aggregates nodes node0+wv*16 .. +16 (register acc, 8 rows in
//   flight), writes bf16 rows into sagg[128][136] (pad 136 -> 2-way/conflict-free).
// Phase C: wave wv owns 16-col slice nt=wv with its 8 B-fragments in registers;
//   loops 8 row-subtiles: A-agg frags from LDS, A-root frags from global (L1/L2),
//   8 MFMA, bias(+relu), store.

__global__ __launch_bounds__(512, 4) void k_fused(const ushort* __restrict__ hin,
                                                  const int* __restrict__ rowptr,
                                                  const int* __restrict__ eidx,
                                                  const ushort* __restrict__ Wt,
                                                  const float* __restrict__ bias,
                                                  void* __restrict__ outp,
                                                  int n, int relu, int outBf16) {
    __shared__ ushort sagg[128][136];

    int t = threadIdx.x;
    int wv = t >> 6;          // 0..7
    int lane = t & 63;
    int eg = lane >> 4;       // 0..3
    int c16 = lane & 15;      // 16B column chunk
    int node0 = blockIdx.x * 128;

    const uint4* base = reinterpret_cast<const uint4*>(hin);  // 16 uint4 per row

    // ---- Phase B: aggregate 16 nodes per wave ----
    for (int k = 0; k < 16; ++k) {
        int u = node0 + wv * 16 + k;
        int beg = 0, end = 0;
        if (u < n) { beg = rowptr[u]; end = rowptr[u + 1]; }

        float acc[8];
#pragma unroll
        for (int i = 0; i < 8; ++i) acc[i] = 0.f;

        int e = beg;
        for (; e + 8 <= end; e += 8) {
            int n0 = eidx[e + eg];
            int n1 = eidx[e + 4 + eg];
            uint4 va = base[(size_t)n0 * 16 + c16];
            uint4 vb = base[(size_t)n1 * 16 + c16];
            acc[0] += __uint_as_float(va.x << 16);
            acc[1] += __uint_as_float(va.x & 0xffff0000u);
            acc[2] += __uint_as_float(va.y << 16);
            acc[3] += __uint_as_float(va.y & 0xffff0000u);
            acc[4] += __uint_as_float(va.z << 16);
            acc[5] += __uint_as_float(va.z & 0xffff0000u);
            acc[6] += __uint_as_float(va.w << 16);
            acc[7] += __uint_as_float(va.w & 0xffff0000u);
            acc[0] += __uint_as_float(vb.x << 16);
            acc[1] += __uint_as_float(vb.x & 0xffff0000u);
            acc[2] += __uint_as_float(vb.y << 16);
            acc[3] += __uint_as_float(vb.y & 0xffff0000u);
            acc[4] += __uint_as_float(vb.z << 16);
            acc[5] += __uint_as_float(vb.z & 0xffff0000u);
            acc[6] += __uint_as_float(vb.w << 16);
            acc[7] += __uint_as_float(vb.w & 0xffff0000u);
        }
        for (; e < end; e += 4) {
            int ee = e + eg;
            if (ee < end) {
                int n0 = eidx[ee];
                uint4 va = base[(size_t)n0 * 16 + c16];
                acc[0] += __uint_as_float(va.x << 16);
                acc[1] += __uint_as_float(va.x & 0xffff0000u);
                acc[2] += __uint_as_float(va.y << 16);
                acc[3] += __uint_as_float(va.y & 0xffff0000u);
                acc[4] += __uint_as_float(va.z << 16);
                acc[5] += __uint_as_float(va.z & 0xffff0000u);
                acc[6] += __uint_as_float(va.w << 16);
                acc[7] += __uint_as_float(va.w & 0xffff0000u);
            }
        }

#pragma unroll
        for (int i = 0; i < 8; ++i) {
            acc[i] += __shfl_xor(acc[i], 16);
            acc[i] += __shfl_xor(acc[i], 32);
        }

        if (eg == 0) {
            float inv = 1.0f / fmaxf((float)(end - beg), 1.0f);
            uint4 o;
            o.x = ((uint)f2bf(acc[1] * inv) << 16) | (uint)f2bf(acc[0] * inv);
            o.y = ((uint)f2bf(acc[3] * inv) << 16) | (uint)f2bf(acc[2] * inv);
            o.z = ((uint)f2bf(acc[5] * inv) << 16) | (uint)f2bf(acc[4] * inv);
            o.w = ((uint)f2bf(acc[7] * inv) << 16) | (uint)f2bf(acc[6] * inv);
            *reinterpret_cast<uint4*>(&sagg[wv * 16 + k][c16 * 8]) = o;
        }
    }
    __syncthreads();

    // ---- Phase C: GEMM for this block's 128 rows ----
    int lr = lane & 15;
    int lk = lane >> 4;
    int nt = wv;              // 16-col slice

    short8v bf[8];
    const ushort* wbase = Wt + (size_t)(nt * 16 + lr) * 256 + lk * 8;
#pragma unroll
    for (int ks = 0; ks < 8; ++ks)
        bf[ks] = *reinterpret_cast<const short8v*>(wbase + ks * 32);

    int col = nt * 16 + lr;
    float bv = bias[col];

#pragma unroll
    for (int sub = 0; sub < 8; ++sub) {
        int m0 = sub * 16;
        int arow = node0 + m0 + lr;
        if (arow >= n) arow = n - 1;  // loads clamped; stores guarded
        const ushort* aroot = hin + (size_t)arow * DD + lk * 8;

        f32x4 acc = (f32x4){0.f, 0.f, 0.f, 0.f};
#pragma unroll
        for (int ks = 0; ks < 4; ++ks) {
            short8v af = *reinterpret_cast<const short8v*>(&sagg[m0 + lr][ks * 32 + lk * 8]);
            acc = __builtin_amdgcn_mfma_f32_16x16x32_bf16(af, bf[ks], acc, 0, 0, 0);
        }
#pragma unroll
        for (int ks = 0; ks < 4; ++ks) {
            short8v af = *reinterpret_cast<const short8v*>(aroot + ks * 32);
            acc = __builtin_amdgcn_mfma_f32_16x16x32_bf16(af, bf[ks + 4], acc, 0, 0, 0);
        }

        int row0 = node0 + m0 + lk * 4;
#pragma unroll
        for (int r = 0; r < 4; ++r) {
            int row = row0 + r;
            if (row < n) {
                float v = acc[r] + bv;
                if (relu) v = fmaxf(v, 0.f);
                if (outBf16) {
                    reinterpret_cast<ushort*>(outp)[(size_t)row * DD + col] = f2bf(v);
                } else {
                    reinterpret_cast<float*>(outp)[(size_t)row * DD + col] = v;
                }
            }
        }
    }
}

// ---------------- launch ----------------

extern "C" void kernel_launch(void* const* d_in, const int* in_sizes, int n_in,
                              void* d_out, int out_size, void* d_ws, size_t ws_size,
                              hipStream_t stream) {
    const float* x   = (const float*)d_in[0];
    const int*   ei  = (const int*)d_in[1];
    const float* Wl1 = (const float*)d_in[2];
    const float* Wr1 = (const float*)d_in[3];
    const float* b1  = (const float*)d_in[4];
    const float* Wl2 = (const float*)d_in[5];
    const float* Wr2 = (const float*)d_in[6];
    const float* b2  = (const float*)d_in[7];
    float* out = (float*)d_out;

    int n = in_sizes[0] / DD;
    int E = in_sizes[1] / 2;

    int NB   = (n + 255) >> 8;          // buckets (<=256 for n<=65536)
    int nblk = (E + CHUNK - 1) / CHUNK; // partition chunks

    char* ws = (char*)d_ws;
    size_t off = 0;
    auto take = [&](size_t bytes) -> void* {
        void* p = ws + off;
        off = (off + bytes + 255) & ~(size_t)255;
        return p;
    };
    int* cnt       = (int*)take((size_t)n * 4);
    int* rowptr    = (int*)take(((size_t)n + 1) * 4);
    int* incl      = (int*)take((size_t)n * 4);
    int* bsum      = (int*)take(1024);
    int* hist      = (int*)take((size_t)nblk * NB * 4);
    int* bbase     = (int*)take(((size_t)NB + 1) * 4);
    int* eidx      = (int*)take((size_t)E * 4);
    uint2* pairs   = (uint2*)take((size_t)E * 8);
    ushort* xbf    = (ushort*)take((size_t)n * DD * 2);
    ushort* hbf    = (ushort*)take((size_t)n * DD * 2);
    ushort* Wt1    = (ushort*)take((size_t)DD * 256 * 2);
    ushort* Wt2    = (ushort*)take((size_t)DD * 256 * 2);

    int scanBlocks = (n + 255) / 256;

    // CSR build
    k_hist<<<nblk, 256, 0, stream>>>(ei, hist, E, NB);
    k_hscan<<<1, 1024, 0, stream>>>(hist, bbase, nblk, NB, E);
    k_scatter<<<nblk, 256, 0, stream>>>(ei, hist, pairs, E, NB);
    k_cntb<<<NB, 256, 0, stream>>>(pairs, bbase, cnt, n);
    k_scan1<<<scanBlocks, 256, 0, stream>>>(cnt, incl, bsum, n);
    k_scan2<<<1, 256, 0, stream>>>(bsum, scanBlocks);
    k_scan3<<<scanBlocks, 256, 0, stream>>>(cnt, incl, bsum, rowptr, n, E);
    k_fill3<<<NB, 256, 0, stream>>>(pairs, bbase, rowptr, eidx, n);

    // dtype prep
    int n4 = n * DD / 4;
    k_cast<<<(n4 + 255) / 256, 256, 0, stream>>>(x, xbf, n4);
    k_prepw<<<128, 256, 0, stream>>>(Wl1, Wr1, Wt1);
    k_prepw<<<128, 256, 0, stream>>>(Wl2, Wr2, Wt2);

    int fusedBlocks = (n + 127) / 128;

    // Layer 1: hbf = relu(mean_agg(xbf) @ Wl1 + b1 + xbf @ Wr1)   [bf16 out]
    k_fused<<<fusedBlocks, 512, 0, stream>>>(xbf, rowptr, eidx, Wt1, b1, hbf, n, 1, 1);
    // Layer 2: out = mean_agg(hbf) @ Wl2 + b2 + hbf @ Wr2          [fp32 out]
    k_fused<<<fusedBlocks, 512, 0, stream>>>(hbf, rowptr, eidx, Wt2, b2, out, n, 0, 0);
}

// Round 11
// 186.944 us; speedup vs baseline: 1.1109x; 1.1109x over previous
//
#include <hip/hip_runtime.h>
#include <hip/hip_bf16.h>

#define DD 128
#define BSH 8          // 256 nodes per bucket (CSR build)
#define CHUNK 4096     // edges per partition block
#define MM_STREAMS 1024

typedef __attribute__((ext_vector_type(8))) short short8v;
typedef __attribute__((ext_vector_type(4))) float f32x4;

static __device__ __forceinline__ ushort f2bf(float f) {
    __hip_bfloat16 b = __float2bfloat16(f);
    return *reinterpret_cast<ushort*>(&b);
}

// ---------------- CSR build: chunked radix partition ----------------

__global__ __launch_bounds__(256) void k_hist(const int* __restrict__ ei,
                                              int* __restrict__ hist, int E, int NB) {
    __shared__ int lh[256];
    int t = threadIdx.x;
    lh[t] = 0;
    __syncthreads();
    int e0 = blockIdx.x * CHUNK;
    int e1 = min(e0 + CHUNK, E);
    for (int e = e0 + t; e < e1; e += 256)
        atomicAdd(&lh[ei[E + e] >> BSH], 1);
    __syncthreads();
    if (t < NB) hist[blockIdx.x * NB + t] = lh[t];
}

__global__ __launch_bounds__(1024) void k_hscan(int* __restrict__ hist,
                                                int* __restrict__ bbase,
                                                int nblk, int NB, int E) {
    __shared__ int part[4][256];
    __shared__ int s[256];
    int t = threadIdx.x;
    int b = t & 255, g = t >> 8;
    int q = (nblk + 3) >> 2;
    int lo = g * q, hi = min(lo + q, nblk);
    int sum = 0;
    if (b < NB)
        for (int blk = lo; blk < hi; ++blk) sum += hist[blk * NB + b];
    part[g][b] = sum;
    __syncthreads();
    if (g == 0) s[b] = part[0][b] + part[1][b] + part[2][b] + part[3][b];
    __syncthreads();
    for (int off = 1; off < 256; off <<= 1) {
        int v = 0;
        if (g == 0 && b >= off) v = s[b - off];
        __syncthreads();
        if (g == 0) s[b] += v;
        __syncthreads();
    }
    int base = (b == 0) ? 0 : s[b - 1];
    if (g == 0 && b < NB) bbase[b] = base;
    if (t == 0) bbase[NB] = E;
    int run = base;
    for (int gg = 0; gg < g; ++gg) run += part[gg][b];
    if (b < NB)
        for (int blk = lo; blk < hi; ++blk) {
            int tmp = hist[blk * NB + b];
            hist[blk * NB + b] = run;
            run += tmp;
        }
}

__global__ __launch_bounds__(256) void k_scatter(const int* __restrict__ ei,
                                                 const int* __restrict__ hist,
                                                 uint2* __restrict__ pairs, int E, int NB) {
    __shared__ int lofs[256];
    __shared__ int lh[256];
    int t = threadIdx.x;
    int blk = blockIdx.x;
    lh[t] = 0;
    if (t < NB) lofs[t] = hist[blk * NB + t];
    __syncthreads();
    int e0 = blk * CHUNK, e1 = min(e0 + CHUNK, E);
    for (int e = e0 + t; e < e1; e += 256) {
        int sN = ei[e];
        int d = ei[E + e];
        int b = d >> BSH;
        int lp = atomicAdd(&lh[b], 1);
        pairs[lofs[b] + lp] = make_uint2((uint)sN, (uint)d);
    }
}

// count + scan + rowptr + fill in ONE kernel: bucket b is self-contained
// because bbase[b] == rowptr[b*256] (buckets are 256 consecutive dst nodes).
__global__ __launch_bounds__(256) void k_csr(const uint2* __restrict__ pairs,
                                             const int* __restrict__ bbase,
                                             int* __restrict__ rowptr,
                                             int* __restrict__ eidx,
                                             int n, int E, int NB) {
    __shared__ int lc[256];
    __shared__ int cur[256];
    int t = threadIdx.x;
    int b = blockIdx.x;
    int node0 = b << BSH;
    lc[t] = 0;
    __syncthreads();
    int r0 = bbase[b], r1 = bbase[b + 1];
    for (int i = r0 + t; i < r1; i += 256)
        atomicAdd(&lc[(int)pairs[i].y - node0], 1);
    __syncthreads();
    int c0 = lc[t];
    // inclusive scan of lc
#pragma unroll
    for (int off = 1; off < 256; off <<= 1) {
        int u = (t >= off) ? lc[t - off] : 0;
        __syncthreads();
        lc[t] += u;
        __syncthreads();
    }
    int rp = r0 + lc[t] - c0;  // exclusive position = rowptr for this node
    int node = node0 + t;
    if (node < n) rowptr[node] = rp;
    if (b == NB - 1 && t == 0) rowptr[n] = E;
    cur[t] = rp;
    __syncthreads();
    for (int i = r0 + t; i < r1; i += 256) {
        uint2 pr = pairs[i];
        int p = atomicAdd(&cur[(int)pr.y - node0], 1);
        eidx[p] = (int)pr.x;
    }
}

// ---------------- fp32 -> bf16 cast ----------------

__global__ __launch_bounds__(256) void k_cast(const float* __restrict__ x,
                                              ushort* __restrict__ xbf, int n4) {
    int i = blockIdx.x * blockDim.x + threadIdx.x;
    if (i >= n4) return;
    float4 v = reinterpret_cast<const float4*>(x)[i];
    ushort4 o;
    o.x = f2bf(v.x); o.y = f2bf(v.y); o.z = f2bf(v.z); o.w = f2bf(v.w);
    reinterpret_cast<ushort4*>(xbf)[i] = o;
}

// ---------------- weight prep: Wt[n][k] = bf16( k<128 ? Wl[k][n] : Wr[k-128][n] ) ----

__global__ __launch_bounds__(256) void k_prepw(const float* __restrict__ Wl,
                                               const float* __restrict__ Wr,
                                               ushort* __restrict__ Wt) {
    int idx = blockIdx.x * 256 + threadIdx.x;   // 128*256 = 32768
    int nn = idx >> 8, k = idx & 255;
    float v = (k < 128) ? Wl[k * 128 + nn] : Wr[(k - 128) * 128 + nn];
    Wt[nn * 256 + k] = f2bf(v);
}

// ---------------- mean aggregation (bf16 in/out, fp32 acc) ----------------
// wave per node; lane = (eg, c16): eg = lane>>4 edge slot, c16 = 16B column
// chunk. 16 gather rows in flight per wave.

#define ACC8(v)                                    \
    acc[0] += __uint_as_float((v).x << 16);        \
    acc[1] += __uint_as_float((v).x & 0xffff0000u);\
    acc[2] += __uint_as_float((v).y << 16);        \
    acc[3] += __uint_as_float((v).y & 0xffff0000u);\
    acc[4] += __uint_as_float((v).z << 16);        \
    acc[5] += __uint_as_float((v).z & 0xffff0000u);\
    acc[6] += __uint_as_float((v).w << 16);        \
    acc[7] += __uint_as_float((v).w & 0xffff0000u);

__global__ __launch_bounds__(256) void k_aggb(const ushort* __restrict__ hin,
                                              const int* __restrict__ rowptr,
                                              const int* __restrict__ eidx,
                                              ushort* __restrict__ aggout, int n) {
    int w = (int)((blockIdx.x * (unsigned)blockDim.x + threadIdx.x) >> 6);
    int lane = threadIdx.x & 63;
    if (w >= n) return;
    int eg = lane >> 4;
    int c16 = lane & 15;
    int beg = rowptr[w], end = rowptr[w + 1];
    const uint4* base = reinterpret_cast<const uint4*>(hin);  // 16 uint4 per row

    float acc[8];
#pragma unroll
    for (int i = 0; i < 8; ++i) acc[i] = 0.f;

    int e = beg;
    for (; e + 16 <= end; e += 16) {
        int id[4];
        uint4 v[4];
#pragma unroll
        for (int j = 0; j < 4; ++j) id[j] = eidx[e + 4 * j + eg];
#pragma unroll
        for (int j = 0; j < 4; ++j) v[j] = base[(size_t)id[j] * 16 + c16];
#pragma unroll
        for (int j = 0; j < 4; ++j) { ACC8(v[j]); }
    }
    for (; e + 8 <= end; e += 8) {
        int i0 = eidx[e + eg];
        int i1 = eidx[e + 4 + eg];
        uint4 va = base[(size_t)i0 * 16 + c16];
        uint4 vb = base[(size_t)i1 * 16 + c16];
        ACC8(va);
        ACC8(vb);
    }
    for (; e < end; e += 4) {
        int ee = e + eg;
        if (ee < end) {
            int i0 = eidx[ee];
            uint4 va = base[(size_t)i0 * 16 + c16];
            ACC8(va);
        }
    }

#pragma unroll
    for (int i = 0; i < 8; ++i) {
        acc[i] += __shfl_xor(acc[i], 16);
        acc[i] += __shfl_xor(acc[i], 32);
    }

    if (eg == 0) {
        float inv = 1.0f / fmaxf((float)(end - beg), 1.0f);
        uint4 o;
        o.x = ((uint)f2bf(acc[1] * inv) << 16) | (uint)f2bf(acc[0] * inv);
        o.y = ((uint)f2bf(acc[3] * inv) << 16) | (uint)f2bf(acc[2] * inv);
        o.z = ((uint)f2bf(acc[5] * inv) << 16) | (uint)f2bf(acc[4] * inv);
        o.w = ((uint)f2bf(acc[7] * inv) << 16) | (uint)f2bf(acc[6] * inv);
        reinterpret_cast<uint4*>(aggout)[(size_t)w * 16 + c16] = o;
    }
}

// ---------------- MFMA GEMM, persistent waves, register-resident B ----------------
// Wave gw: nt = gw&7 (16-col slice), tile-stream = gw>>3. Preloads its 8
// B-fragments (32 VGPR) once, then grid-strides over 16-row tiles.

__global__ __launch_bounds__(256, 8) void k_mm(const ushort* __restrict__ Alow,
                                               const ushort* __restrict__ Ahigh,
                                               const ushort* __restrict__ Wt,
                                               const float* __restrict__ bias,
                                               void* __restrict__ outp,
                                               int n, int ntiles, int relu, int outBf16) {
    int t = threadIdx.x;
    int wv = t >> 6;
    int l = t & 63;
    int lr = l & 15;
    int lk = l >> 4;
    int gw = blockIdx.x * 4 + wv;
    int nt = gw & 7;
    int stream = gw >> 3;

    short8v bf[8];
    const ushort* wbase = Wt + (size_t)(nt * 16 + lr) * 256 + lk * 8;
#pragma unroll
    for (int ks = 0; ks < 8; ++ks)
        bf[ks] = *reinterpret_cast<const short8v*>(wbase + ks * 32);

    int col = nt * 16 + lr;
    float bv = bias[col];

    for (int tile = stream; tile < ntiles; tile += MM_STREAMS) {
        int m0 = tile * 16;
        int arow = m0 + lr;
        if (arow >= n) arow = n - 1;  // loads clamped; stores guarded
        const ushort* alo = Alow + (size_t)arow * DD + lk * 8;
        const ushort* ahi = Ahigh + (size_t)arow * DD + lk * 8;

        f32x4 acc = (f32x4){0.f, 0.f, 0.f, 0.f};
#pragma unroll
        for (int ks = 0; ks < 4; ++ks) {
            short8v af = *reinterpret_cast<const short8v*>(alo + ks * 32);
            acc = __builtin_amdgcn_mfma_f32_16x16x32_bf16(af, bf[ks], acc, 0, 0, 0);
        }
#pragma unroll
        for (int ks = 0; ks < 4; ++ks) {
            short8v af = *reinterpret_cast<const short8v*>(ahi + ks * 32);
            acc = __builtin_amdgcn_mfma_f32_16x16x32_bf16(af, bf[ks + 4], acc, 0, 0, 0);
        }

        int row0 = m0 + lk * 4;
#pragma unroll
        for (int r = 0; r < 4; ++r) {
            int row = row0 + r;
            if (row < n) {
                float v = acc[r] + bv;
                if (relu) v = fmaxf(v, 0.f);
                if (outBf16) {
                    reinterpret_cast<ushort*>(outp)[(size_t)row * DD + col] = f2bf(v);
                } else {
                    reinterpret_cast<float*>(outp)[(size_t)row * DD + col] = v;
                }
            }
        }
    }
}

// ---------------- launch ----------------

extern "C" void kernel_launch(void* const* d_in, const int* in_sizes, int n_in,
                              void* d_out, int out_size, void* d_ws, size_t ws_size,
                              hipStream_t stream) {
    const float* x   = (const float*)d_in[0];
    const int*   ei  = (const int*)d_in[1];
    const float* Wl1 = (const float*)d_in[2];
    const float* Wr1 = (const float*)d_in[3];
    const float* b1  = (const float*)d_in[4];
    const float* Wl2 = (const float*)d_in[5];
    const float* Wr2 = (const float*)d_in[6];
    const float* b2  = (const float*)d_in[7];
    float* out = (float*)d_out;

    int n = in_sizes[0] / DD;
    int E = in_sizes[1] / 2;

    int NB   = (n + 255) >> 8;          // buckets (<=256 for n<=65536)
    int nblk = (E + CHUNK - 1) / CHUNK; // partition chunks

    char* ws = (char*)d_ws;
    size_t off = 0;
    auto take = [&](size_t bytes) -> void* {
        void* p = ws + off;
        off = (off + bytes + 255) & ~(size_t)255;
        return p;
    };
    int* rowptr    = (int*)take(((size_t)n + 1) * 4);
    int* hist      = (int*)take((size_t)nblk * NB * 4);
    int* bbase     = (int*)take(((size_t)NB + 1) * 4);
    int* eidx      = (int*)take((size_t)E * 4);
    uint2* pairs   = (uint2*)take((size_t)E * 8);
    ushort* xbf    = (ushort*)take((size_t)n * DD * 2);
    ushort* hbf    = (ushort*)take((size_t)n * DD * 2);
    ushort* aggbf  = (ushort*)take((size_t)n * DD * 2);
    ushort* Wt1    = (ushort*)take((size_t)DD * 256 * 2);
    ushort* Wt2    = (ushort*)take((size_t)DD * 256 * 2);

    int ntiles = (n + 15) / 16;

    // CSR build (4 launches)
    k_hist<<<nblk, 256, 0, stream>>>(ei, hist, E, NB);
    k_hscan<<<1, 1024, 0, stream>>>(hist, bbase, nblk, NB, E);
    k_scatter<<<nblk, 256, 0, stream>>>(ei, hist, pairs, E, NB);
    k_csr<<<NB, 256, 0, stream>>>(pairs, bbase, rowptr, eidx, n, E, NB);

    // dtype prep
    int n4 = n * DD / 4;
    k_cast<<<(n4 + 255) / 256, 256, 0, stream>>>(x, xbf, n4);
    k_prepw<<<128, 256, 0, stream>>>(Wl1, Wr1, Wt1);
    k_prepw<<<128, 256, 0, stream>>>(Wl2, Wr2, Wt2);

    int aggBlocks = (n + 3) / 4;            // 4 waves (nodes) / block
    int mmBlocks  = MM_STREAMS * 8 / 4;     // 2048 blocks (8192 waves)

    // Layer 1: h = relu(mean_agg(xbf) @ Wl1 + b1 + xbf @ Wr1)
    k_aggb<<<aggBlocks, 256, 0, stream>>>(xbf, rowptr, eidx, aggbf, n);
    k_mm<<<mmBlocks, 256, 0, stream>>>(aggbf, xbf, Wt1, b1, hbf, n, ntiles, 1, 1);
    // Layer 2: out = mean_agg(hbf) @ Wl2 + b2 + hbf @ Wr2
    k_aggb<<<aggBlocks, 256, 0, stream>>>(hbf, rowptr, eidx, aggbf, n);
    k_mm<<<mmBlocks, 256, 0, stream>>>(aggbf, hbf, Wt2, b2, out, n, ntiles, 0, 0);
}

// Round 12
// 182.536 us; speedup vs baseline: 1.1377x; 1.0241x over previous
//
#include <hip/hip_runtime.h>
#include <hip/hip_bf16.h>

#define DD 128
#define BSH 8          // 256 nodes per bucket (CSR build)
#define CHUNK 4096     // edges per partition block
#define MM_STREAMS 1024

typedef __attribute__((ext_vector_type(8))) short short8v;
typedef __attribute__((ext_vector_type(4))) float f32x4;

static __device__ __forceinline__ ushort f2bf(float f) {
    __hip_bfloat16 b = __float2bfloat16(f);
    return *reinterpret_cast<ushort*>(&b);
}

// ---------------- merged prep: hist + cast + prepw1 + prepw2 ----------------
// block roles by blockIdx range (all independent).

__global__ __launch_bounds__(256) void k_prep(const int* __restrict__ ei,
                                              int* __restrict__ hist, int E, int NB, int nblk,
                                              const float* __restrict__ x,
                                              ushort* __restrict__ xbf, int n4, int castBlocks,
                                              const float* __restrict__ Wl1,
                                              const float* __restrict__ Wr1,
                                              ushort* __restrict__ Wt1,
                                              const float* __restrict__ Wl2,
                                              const float* __restrict__ Wr2,
                                              ushort* __restrict__ Wt2) {
    __shared__ int lh[256];
    int t = threadIdx.x;
    int b = blockIdx.x;

    if (b < nblk) {
        // histogram over this chunk (bucket = dst>>BSH)
        lh[t] = 0;
        __syncthreads();
        int e0 = b * CHUNK;
        int e1 = min(e0 + CHUNK, E);
        for (int e = e0 + t; e < e1; e += 256)
            atomicAdd(&lh[ei[E + e] >> BSH], 1);
        __syncthreads();
        if (t < NB) hist[b * NB + t] = lh[t];
        return;
    }
    b -= nblk;
    if (b < castBlocks) {
        int i = b * 256 + t;
        if (i < n4) {
            float4 v = reinterpret_cast<const float4*>(x)[i];
            ushort4 o;
            o.x = f2bf(v.x); o.y = f2bf(v.y); o.z = f2bf(v.z); o.w = f2bf(v.w);
            reinterpret_cast<ushort4*>(xbf)[i] = o;
        }
        return;
    }
    b -= castBlocks;
    {
        const float* Wl = (b < 128) ? Wl1 : Wl2;
        const float* Wr = (b < 128) ? Wr1 : Wr2;
        ushort* Wt = (b < 128) ? Wt1 : Wt2;
        int idx = (b & 127) * 256 + t;   // 128*256 = 32768
        int nn = idx >> 8, k = idx & 255;
        float v = (k < 128) ? Wl[k * 128 + nn] : Wr[(k - 128) * 128 + nn];
        Wt[nn * 256 + k] = f2bf(v);
    }
}

__global__ __launch_bounds__(1024) void k_hscan(int* __restrict__ hist,
                                                int* __restrict__ bbase,
                                                int nblk, int NB, int E) {
    __shared__ int part[4][256];
    __shared__ int s[256];
    int t = threadIdx.x;
    int b = t & 255, g = t >> 8;
    int q = (nblk + 3) >> 2;
    int lo = g * q, hi = min(lo + q, nblk);
    int sum = 0;
    if (b < NB)
        for (int blk = lo; blk < hi; ++blk) sum += hist[blk * NB + b];
    part[g][b] = sum;
    __syncthreads();
    if (g == 0) s[b] = part[0][b] + part[1][b] + part[2][b] + part[3][b];
    __syncthreads();
    for (int off = 1; off < 256; off <<= 1) {
        int v = 0;
        if (g == 0 && b >= off) v = s[b - off];
        __syncthreads();
        if (g == 0) s[b] += v;
        __syncthreads();
    }
    int base = (b == 0) ? 0 : s[b - 1];
    if (g == 0 && b < NB) bbase[b] = base;
    if (t == 0) bbase[NB] = E;
    int run = base;
    for (int gg = 0; gg < g; ++gg) run += part[gg][b];
    if (b < NB)
        for (int blk = lo; blk < hi; ++blk) {
            int tmp = hist[blk * NB + b];
            hist[blk * NB + b] = run;
            run += tmp;
        }
}

// scatter packed records (dstlocal<<16 | src), u16 src since n < 65536
__global__ __launch_bounds__(256) void k_scatter(const int* __restrict__ ei,
                                                 const int* __restrict__ hist,
                                                 uint* __restrict__ pairs, int E, int NB) {
    __shared__ int lofs[256];
    __shared__ int lh[256];
    int t = threadIdx.x;
    int blk = blockIdx.x;
    lh[t] = 0;
    if (t < NB) lofs[t] = hist[blk * NB + t];
    __syncthreads();
    int e0 = blk * CHUNK, e1 = min(e0 + CHUNK, E);
    for (int e = e0 + t; e < e1; e += 256) {
        int sN = ei[e];
        int d = ei[E + e];
        int b = d >> BSH;
        int lp = atomicAdd(&lh[b], 1);
        pairs[lofs[b] + lp] = ((uint)(d & 255) << 16) | (uint)sN;
    }
}

// count + scan + rowptr + fill in ONE kernel (bbase[b] == rowptr[b*256])
__global__ __launch_bounds__(256) void k_csr(const uint* __restrict__ pairs,
                                             const int* __restrict__ bbase,
                                             int* __restrict__ rowptr,
                                             ushort* __restrict__ eidx,
                                             int n, int E, int NB) {
    __shared__ int lc[256];
    __shared__ int cur[256];
    int t = threadIdx.x;
    int b = blockIdx.x;
    int node0 = b << BSH;
    lc[t] = 0;
    __syncthreads();
    int r0 = bbase[b], r1 = bbase[b + 1];
    for (int i = r0 + t; i < r1; i += 256)
        atomicAdd(&lc[pairs[i] >> 16], 1);
    __syncthreads();
    int c0 = lc[t];
#pragma unroll
    for (int off = 1; off < 256; off <<= 1) {
        int u = (t >= off) ? lc[t - off] : 0;
        __syncthreads();
        lc[t] += u;
        __syncthreads();
    }
    int rp = r0 + lc[t] - c0;
    int node = node0 + t;
    if (node < n) rowptr[node] = rp;
    if (b == NB - 1 && t == 0) rowptr[n] = E;
    cur[t] = rp;
    __syncthreads();
    for (int i = r0 + t; i < r1; i += 256) {
        uint pr = pairs[i];
        int p = atomicAdd(&cur[pr >> 16], 1);
        eidx[p] = (ushort)(pr & 0xFFFFu);
    }
}

// ---------------- mean aggregation (bf16 in/out, fp32 acc) ----------------
// 16-lane group per node (4 nodes/wave): group gathers full 256B rows
// (16 lanes x uint4), 4 rows in flight; no cross-lane reduce needed.

#define ACC8(v)                                    \
    acc[0] += __uint_as_float((v).x << 16);        \
    acc[1] += __uint_as_float((v).x & 0xffff0000u);\
    acc[2] += __uint_as_float((v).y << 16);        \
    acc[3] += __uint_as_float((v).y & 0xffff0000u);\
    acc[4] += __uint_as_float((v).z << 16);        \
    acc[5] += __uint_as_float((v).z & 0xffff0000u);\
    acc[6] += __uint_as_float((v).w << 16);        \
    acc[7] += __uint_as_float((v).w & 0xffff0000u);

__global__ __launch_bounds__(256) void k_aggb(const ushort* __restrict__ hin,
                                              const int* __restrict__ rowptr,
                                              const ushort* __restrict__ eidx,
                                              ushort* __restrict__ aggout, int n) {
    int wave = (int)((blockIdx.x * (unsigned)blockDim.x + threadIdx.x) >> 6);
    int lane = threadIdx.x & 63;
    int grp = lane >> 4;      // node within wave
    int c16 = lane & 15;      // 16B column chunk
    int node = wave * 4 + grp;
    if (node >= n) return;

    int beg = rowptr[node], end = rowptr[node + 1];
    const uint4* base = reinterpret_cast<const uint4*>(hin);  // 16 uint4 per row

    float acc[8];
#pragma unroll
    for (int i = 0; i < 8; ++i) acc[i] = 0.f;

    for (int e = beg; e < end; e += 4) {
        int m = end - e;
        int i0 = eidx[e];
        int i1 = eidx[e + (m > 1 ? 1 : 0)];
        int i2 = eidx[e + (m > 2 ? 2 : 0)];
        int i3 = eidx[e + (m > 3 ? 3 : 0)];
        uint4 v0 = base[(size_t)i0 * 16 + c16];
        uint4 v1 = base[(size_t)i1 * 16 + c16];
        uint4 v2 = base[(size_t)i2 * 16 + c16];
        uint4 v3 = base[(size_t)i3 * 16 + c16];
        ACC8(v0);
        if (m > 1) { ACC8(v1); }
        if (m > 2) { ACC8(v2); }
        if (m > 3) { ACC8(v3); }
    }

    float inv = 1.0f / fmaxf((float)(end - beg), 1.0f);
    uint4 o;
    o.x = ((uint)f2bf(acc[1] * inv) << 16) | (uint)f2bf(acc[0] * inv);
    o.y = ((uint)f2bf(acc[3] * inv) << 16) | (uint)f2bf(acc[2] * inv);
    o.z = ((uint)f2bf(acc[5] * inv) << 16) | (uint)f2bf(acc[4] * inv);
    o.w = ((uint)f2bf(acc[7] * inv) << 16) | (uint)f2bf(acc[6] * inv);
    reinterpret_cast<uint4*>(aggout)[(size_t)node * 16 + c16] = o;
}

// ---------------- MFMA GEMM, persistent waves, register-resident B ----------------

__global__ __launch_bounds__(256, 8) void k_mm(const ushort* __restrict__ Alow,
                                               const ushort* __restrict__ Ahigh,
                                               const ushort* __restrict__ Wt,
                                               const float* __restrict__ bias,
                                               void* __restrict__ outp,
                                               int n, int ntiles, int relu, int outBf16) {
    int t = threadIdx.x;
    int wv = t >> 6;
    int l = t & 63;
    int lr = l & 15;
    int lk = l >> 4;
    int gw = blockIdx.x * 4 + wv;
    int nt = gw & 7;
    int stream = gw >> 3;

    short8v bf[8];
    const ushort* wbase = Wt + (size_t)(nt * 16 + lr) * 256 + lk * 8;
#pragma unroll
    for (int ks = 0; ks < 8; ++ks)
        bf[ks] = *reinterpret_cast<const short8v*>(wbase + ks * 32);

    int col = nt * 16 + lr;
    float bv = bias[col];

    for (int tile = stream; tile < ntiles; tile += MM_STREAMS) {
        int m0 = tile * 16;
        int arow = m0 + lr;
        if (arow >= n) arow = n - 1;  // loads clamped; stores guarded
        const ushort* alo = Alow + (size_t)arow * DD + lk * 8;
        const ushort* ahi = Ahigh + (size_t)arow * DD + lk * 8;

        f32x4 acc = (f32x4){0.f, 0.f, 0.f, 0.f};
#pragma unroll
        for (int ks = 0; ks < 4; ++ks) {
            short8v af = *reinterpret_cast<const short8v*>(alo + ks * 32);
            acc = __builtin_amdgcn_mfma_f32_16x16x32_bf16(af, bf[ks], acc, 0, 0, 0);
        }
#pragma unroll
        for (int ks = 0; ks < 4; ++ks) {
            short8v af = *reinterpret_cast<const short8v*>(ahi + ks * 32);
            acc = __builtin_amdgcn_mfma_f32_16x16x32_bf16(af, bf[ks + 4], acc, 0, 0, 0);
        }

        int row0 = m0 + lk * 4;
#pragma unroll
        for (int r = 0; r < 4; ++r) {
            int row = row0 + r;
            if (row < n) {
                float v = acc[r] + bv;
                if (relu) v = fmaxf(v, 0.f);
                if (outBf16) {
                    reinterpret_cast<ushort*>(outp)[(size_t)row * DD + col] = f2bf(v);
                } else {
                    reinterpret_cast<float*>(outp)[(size_t)row * DD + col] = v;
                }
            }
        }
    }
}

// ---------------- launch ----------------

extern "C" void kernel_launch(void* const* d_in, const int* in_sizes, int n_in,
                              void* d_out, int out_size, void* d_ws, size_t ws_size,
                              hipStream_t stream) {
    const float* x   = (const float*)d_in[0];
    const int*   ei  = (const int*)d_in[1];
    const float* Wl1 = (const float*)d_in[2];
    const float* Wr1 = (const float*)d_in[3];
    const float* b1  = (const float*)d_in[4];
    const float* Wl2 = (const float*)d_in[5];
    const float* Wr2 = (const float*)d_in[6];
    const float* b2  = (const float*)d_in[7];
    float* out = (float*)d_out;

    int n = in_sizes[0] / DD;
    int E = in_sizes[1] / 2;

    int NB   = (n + 255) >> 8;          // buckets (<=256 for n<=65536)
    int nblk = (E + CHUNK - 1) / CHUNK; // partition chunks

    char* ws = (char*)d_ws;
    size_t off = 0;
    auto take = [&](size_t bytes) -> void* {
        void* p = ws + off;
        off = (off + bytes + 255) & ~(size_t)255;
        return p;
    };
    int* rowptr    = (int*)take(((size_t)n + 1) * 4);
    int* hist      = (int*)take((size_t)nblk * NB * 4);
    int* bbase     = (int*)take(((size_t)NB + 1) * 4);
    ushort* eidx   = (ushort*)take((size_t)E * 2 + 16);
    uint* pairs    = (uint*)take((size_t)E * 4);
    ushort* xbf    = (ushort*)take((size_t)n * DD * 2);
    ushort* hbf    = (ushort*)take((size_t)n * DD * 2);
    ushort* aggbf  = (ushort*)take((size_t)n * DD * 2);
    ushort* Wt1    = (ushort*)take((size_t)DD * 256 * 2);
    ushort* Wt2    = (ushort*)take((size_t)DD * 256 * 2);

    int ntiles = (n + 15) / 16;
    int n4 = n * DD / 4;
    int castBlocks = (n4 + 255) / 256;
    int prepBlocks = nblk + castBlocks + 256;

    // prep: hist + cast + both weight transposes in one launch
    k_prep<<<prepBlocks, 256, 0, stream>>>(ei, hist, E, NB, nblk,
                                           x, xbf, n4, castBlocks,
                                           Wl1, Wr1, Wt1, Wl2, Wr2, Wt2);
    k_hscan<<<1, 1024, 0, stream>>>(hist, bbase, nblk, NB, E);
    k_scatter<<<nblk, 256, 0, stream>>>(ei, hist, pairs, E, NB);
    k_csr<<<NB, 256, 0, stream>>>(pairs, bbase, rowptr, eidx, n, E, NB);

    int aggBlocks = (n + 15) / 16;          // 16 nodes / block (4 waves x 4 nodes)
    int mmBlocks  = MM_STREAMS * 8 / 4;     // 2048 blocks (8192 waves)

    // Layer 1: h = relu(mean_agg(xbf) @ Wl1 + b1 + xbf @ Wr1)
    k_aggb<<<aggBlocks, 256, 0, stream>>>(xbf, rowptr, eidx, aggbf, n);
    k_mm<<<mmBlocks, 256, 0, stream>>>(aggbf, xbf, Wt1, b1, hbf, n, ntiles, 1, 1);
    // Layer 2: out = mean_agg(hbf) @ Wl2 + b2 + hbf @ Wr2
    k_aggb<<<aggBlocks, 256, 0, stream>>>(hbf, rowptr, eidx, aggbf, n);
    k_mm<<<mmBlocks, 256, 0, stream>>>(aggbf, hbf, Wt2, b2, out, n, ntiles, 0, 0);
}

// Round 13
// 159.901 us; speedup vs baseline: 1.2987x; 1.1416x over previous
//
#include <hip/hip_runtime.h>
#include <hip/hip_bf16.h>

#define DD 128
#define BSH 8          // 256 nodes per bucket (CSR build)
#define CHUNK 4096     // edges per partition block

typedef __attribute__((ext_vector_type(8))) short short8v;
typedef __attribute__((ext_vector_type(4))) float f32x4;

static __device__ __forceinline__ ushort f2bf(float f) {
    __hip_bfloat16 b = __float2bfloat16(f);
    return *reinterpret_cast<ushort*>(&b);
}

// ---------------- merged prep: hist + cast + prepw1 + prepw2 ----------------

__global__ __launch_bounds__(256) void k_prep(const int* __restrict__ ei,
                                              int* __restrict__ hist, int E, int NB, int nblk,
                                              const float* __restrict__ x,
                                              ushort* __restrict__ xbf, int n4, int castBlocks,
                                              const float* __restrict__ Wl1,
                                              const float* __restrict__ Wr1,
                                              ushort* __restrict__ Wt1,
                                              const float* __restrict__ Wl2,
                                              const float* __restrict__ Wr2,
                                              ushort* __restrict__ Wt2) {
    __shared__ int lh[256];
    int t = threadIdx.x;
    int b = blockIdx.x;

    if (b < nblk) {
        lh[t] = 0;
        __syncthreads();
        int e0 = b * CHUNK;
        int e1 = min(e0 + CHUNK, E);
        for (int e = e0 + t; e < e1; e += 256)
            atomicAdd(&lh[ei[E + e] >> BSH], 1);
        __syncthreads();
        if (t < NB) hist[b * NB + t] = lh[t];
        return;
    }
    b -= nblk;
    if (b < castBlocks) {
        int i = b * 256 + t;
        if (i < n4) {
            float4 v = reinterpret_cast<const float4*>(x)[i];
            ushort4 o;
            o.x = f2bf(v.x); o.y = f2bf(v.y); o.z = f2bf(v.z); o.w = f2bf(v.w);
            reinterpret_cast<ushort4*>(xbf)[i] = o;
        }
        return;
    }
    b -= castBlocks;
    {
        const float* Wl = (b < 128) ? Wl1 : Wl2;
        const float* Wr = (b < 128) ? Wr1 : Wr2;
        ushort* Wt = (b < 128) ? Wt1 : Wt2;
        int idx = (b & 127) * 256 + t;   // 128*256 = 32768
        int nn = idx >> 8, k = idx & 255;
        float v = (k < 128) ? Wl[k * 128 + nn] : Wr[(k - 128) * 128 + nn];
        Wt[nn * 256 + k] = f2bf(v);
    }
}

__global__ __launch_bounds__(1024) void k_hscan(int* __restrict__ hist,
                                                int* __restrict__ bbase,
                                                int nblk, int NB, int E) {
    __shared__ int part[4][256];
    __shared__ int s[256];
    int t = threadIdx.x;
    int b = t & 255, g = t >> 8;
    int q = (nblk + 3) >> 2;
    int lo = g * q, hi = min(lo + q, nblk);
    int sum = 0;
    if (b < NB)
        for (int blk = lo; blk < hi; ++blk) sum += hist[blk * NB + b];
    part[g][b] = sum;
    __syncthreads();
    if (g == 0) s[b] = part[0][b] + part[1][b] + part[2][b] + part[3][b];
    __syncthreads();
    for (int off = 1; off < 256; off <<= 1) {
        int v = 0;
        if (g == 0 && b >= off) v = s[b - off];
        __syncthreads();
        if (g == 0) s[b] += v;
        __syncthreads();
    }
    int base = (b == 0) ? 0 : s[b - 1];
    if (g == 0 && b < NB) bbase[b] = base;
    if (t == 0) bbase[NB] = E;
    int run = base;
    for (int gg = 0; gg < g; ++gg) run += part[gg][b];
    if (b < NB)
        for (int blk = lo; blk < hi; ++blk) {
            int tmp = hist[blk * NB + b];
            hist[blk * NB + b] = run;
            run += tmp;
        }
}

__global__ __launch_bounds__(256) void k_scatter(const int* __restrict__ ei,
                                                 const int* __restrict__ hist,
                                                 uint* __restrict__ pairs, int E, int NB) {
    __shared__ int lofs[256];
    __shared__ int lh[256];
    int t = threadIdx.x;
    int blk = blockIdx.x;
    lh[t] = 0;
    if (t < NB) lofs[t] = hist[blk * NB + t];
    __syncthreads();
    int e0 = blk * CHUNK, e1 = min(e0 + CHUNK, E);
    for (int e = e0 + t; e < e1; e += 256) {
        int sN = ei[e];
        int d = ei[E + e];
        int b = d >> BSH;
        int lp = atomicAdd(&lh[b], 1);
        pairs[lofs[b] + lp] = ((uint)(d & 255) << 16) | (uint)sN;
    }
}

__global__ __launch_bounds__(256) void k_csr(const uint* __restrict__ pairs,
                                             const int* __restrict__ bbase,
                                             int* __restrict__ rowptr,
                                             ushort* __restrict__ eidx,
                                             int n, int E, int NB) {
    __shared__ int lc[256];
    __shared__ int cur[256];
    int t = threadIdx.x;
    int b = blockIdx.x;
    int node0 = b << BSH;
    lc[t] = 0;
    __syncthreads();
    int r0 = bbase[b], r1 = bbase[b + 1];
    for (int i = r0 + t; i < r1; i += 256)
        atomicAdd(&lc[pairs[i] >> 16], 1);
    __syncthreads();
    int c0 = lc[t];
#pragma unroll
    for (int off = 1; off < 256; off <<= 1) {
        int u = (t >= off) ? lc[t - off] : 0;
        __syncthreads();
        lc[t] += u;
        __syncthreads();
    }
    int rp = r0 + lc[t] - c0;
    int node = node0 + t;
    if (node < n) rowptr[node] = rp;
    if (b == NB - 1 && t == 0) rowptr[n] = E;
    cur[t] = rp;
    __syncthreads();
    for (int i = r0 + t; i < r1; i += 256) {
        uint pr = pairs[i];
        int p = atomicAdd(&cur[pr >> 16], 1);
        eidx[p] = (ushort)(pr & 0xFFFFu);
    }
}

// ---------------- mean aggregation (bf16 in/out, fp32 acc) ----------------

#define ACC8(v)                                    \
    acc[0] += __uint_as_float((v).x << 16);        \
    acc[1] += __uint_as_float((v).x & 0xffff0000u);\
    acc[2] += __uint_as_float((v).y << 16);        \
    acc[3] += __uint_as_float((v).y & 0xffff0000u);\
    acc[4] += __uint_as_float((v).z << 16);        \
    acc[5] += __uint_as_float((v).z & 0xffff0000u);\
    acc[6] += __uint_as_float((v).w << 16);        \
    acc[7] += __uint_as_float((v).w & 0xffff0000u);

__global__ __launch_bounds__(256) void k_aggb(const ushort* __restrict__ hin,
                                              const int* __restrict__ rowptr,
                                              const ushort* __restrict__ eidx,
                                              ushort* __restrict__ aggout, int n) {
    int wave = (int)((blockIdx.x * (unsigned)blockDim.x + threadIdx.x) >> 6);
    int lane = threadIdx.x & 63;
    int grp = lane >> 4;      // node within wave
    int c16 = lane & 15;      // 16B column chunk
    int node = wave * 4 + grp;
    if (node >= n) return;

    int beg = rowptr[node], end = rowptr[node + 1];
    const uint4* base = reinterpret_cast<const uint4*>(hin);  // 16 uint4 per row

    float acc[8];
#pragma unroll
    for (int i = 0; i < 8; ++i) acc[i] = 0.f;

    for (int e = beg; e < end; e += 4) {
        int m = end - e;
        int i0 = eidx[e];
        int i1 = eidx[e + (m > 1 ? 1 : 0)];
        int i2 = eidx[e + (m > 2 ? 2 : 0)];
        int i3 = eidx[e + (m > 3 ? 3 : 0)];
        uint4 v0 = base[(size_t)i0 * 16 + c16];
        uint4 v1 = base[(size_t)i1 * 16 + c16];
        uint4 v2 = base[(size_t)i2 * 16 + c16];
        uint4 v3 = base[(size_t)i3 * 16 + c16];
        ACC8(v0);
        if (m > 1) { ACC8(v1); }
        if (m > 2) { ACC8(v2); }
        if (m > 3) { ACC8(v3); }
    }

    float inv = 1.0f / fmaxf((float)(end - beg), 1.0f);
    uint4 o;
    o.x = ((uint)f2bf(acc[1] * inv) << 16) | (uint)f2bf(acc[0] * inv);
    o.y = ((uint)f2bf(acc[3] * inv) << 16) | (uint)f2bf(acc[2] * inv);
    o.z = ((uint)f2bf(acc[5] * inv) << 16) | (uint)f2bf(acc[4] * inv);
    o.w = ((uint)f2bf(acc[7] * inv) << 16) | (uint)f2bf(acc[6] * inv);
    reinterpret_cast<uint4*>(aggout)[(size_t)node * 16 + c16] = o;
}

// ---------------- MFMA GEMM, LDS-staged A (read once), register-resident B ----
// Block = 512 thr / 8 waves / 32 rows. Stage [32 rows][K=256] bf16 tile (16 KB)
// with 16B-chunk XOR swizzle (chunk^row within each 128-col half) -> conflict-free
// staging writes AND ds_read_b128 fragment reads. Wave wv owns 16-col slice wv
// (8 B-frags in registers) and computes 2 row-subtiles of 16.

__global__ __launch_bounds__(512, 8) void k_mm(const ushort* __restrict__ Alow,
                                               const ushort* __restrict__ Ahigh,
                                               const ushort* __restrict__ Wt,
                                               const float* __restrict__ bias,
                                               void* __restrict__ outp,
                                               int n, int relu, int outBf16) {
    __shared__ ushort sA[32][256];   // 16 KB, chunk-swizzled

    int t = threadIdx.x;
    int row0 = blockIdx.x * 32;

    // stage 32 rows x 32 chunks of 16B; 1024 chunk-loads, 2 per thread
#pragma unroll
    for (int i = t; i < 1024; i += 512) {
        int r = i >> 5, c = i & 31;
        int row = row0 + r;
        if (row >= n) row = n - 1;
        const ushort* src = (c < 16) ? (Alow + (size_t)row * DD + c * 8)
                                     : (Ahigh + (size_t)row * DD + (c - 16) * 8);
        uint4 v = *reinterpret_cast<const uint4*>(src);
        int cs = (c & 16) | ((c ^ r) & 15);    // swizzle within half
        *reinterpret_cast<uint4*>(&sA[r][cs * 8]) = v;
    }
    __syncthreads();

    int wv = t >> 6;          // col-slice
    int lane = t & 63;
    int lr = lane & 15;
    int lk = lane >> 4;

    short8v bf[8];
    const ushort* wbase = Wt + (size_t)(wv * 16 + lr) * 256 + lk * 8;
#pragma unroll
    for (int ks = 0; ks < 8; ++ks)
        bf[ks] = *reinterpret_cast<const short8v*>(wbase + ks * 32);

    int col = wv * 16 + lr;
    float bv = bias[col];

#pragma unroll
    for (int sub = 0; sub < 2; ++sub) {
        int m0 = sub * 16;
        int r = m0 + lr;
        f32x4 acc = (f32x4){0.f, 0.f, 0.f, 0.f};
#pragma unroll
        for (int ks = 0; ks < 8; ++ks) {
            int cc = ks * 4 + lk;                       // 16B chunk in K
            int cs = (cc & 16) | ((cc ^ r) & 15);       // same swizzle
            short8v af = *reinterpret_cast<const short8v*>(&sA[r][cs * 8]);
            acc = __builtin_amdgcn_mfma_f32_16x16x32_bf16(af, bf[ks], acc, 0, 0, 0);
        }
        int rowb = row0 + m0 + lk * 4;
#pragma unroll
        for (int q = 0; q < 4; ++q) {
            int row = rowb + q;
            if (row < n) {
                float v = acc[q] + bv;
                if (relu) v = fmaxf(v, 0.f);
                if (outBf16) {
                    reinterpret_cast<ushort*>(outp)[(size_t)row * DD + col] = f2bf(v);
                } else {
                    reinterpret_cast<float*>(outp)[(size_t)row * DD + col] = v;
                }
            }
        }
    }
}

// ---------------- launch ----------------

extern "C" void kernel_launch(void* const* d_in, const int* in_sizes, int n_in,
                              void* d_out, int out_size, void* d_ws, size_t ws_size,
                              hipStream_t stream) {
    const float* x   = (const float*)d_in[0];
    const int*   ei  = (const int*)d_in[1];
    const float* Wl1 = (const float*)d_in[2];
    const float* Wr1 = (const float*)d_in[3];
    const float* b1  = (const float*)d_in[4];
    const float* Wl2 = (const float*)d_in[5];
    const float* Wr2 = (const float*)d_in[6];
    const float* b2  = (const float*)d_in[7];
    float* out = (float*)d_out;

    int n = in_sizes[0] / DD;
    int E = in_sizes[1] / 2;

    int NB   = (n + 255) >> 8;          // buckets (<=256 for n<=65536)
    int nblk = (E + CHUNK - 1) / CHUNK; // partition chunks

    char* ws = (char*)d_ws;
    size_t off = 0;
    auto take = [&](size_t bytes) -> void* {
        void* p = ws + off;
        off = (off + bytes + 255) & ~(size_t)255;
        return p;
    };
    int* rowptr    = (int*)take(((size_t)n + 1) * 4);
    int* hist      = (int*)take((size_t)nblk * NB * 4);
    int* bbase     = (int*)take(((size_t)NB + 1) * 4);
    ushort* eidx   = (ushort*)take((size_t)E * 2 + 16);
    uint* pairs    = (uint*)take((size_t)E * 4);
    ushort* xbf    = (ushort*)take((size_t)n * DD * 2);
    ushort* hbf    = (ushort*)take((size_t)n * DD * 2);
    ushort* aggbf  = (ushort*)take((size_t)n * DD * 2);
    ushort* Wt1    = (ushort*)take((size_t)DD * 256 * 2);
    ushort* Wt2    = (ushort*)take((size_t)DD * 256 * 2);

    int n4 = n * DD / 4;
    int castBlocks = (n4 + 255) / 256;
    int prepBlocks = nblk + castBlocks + 256;

    k_prep<<<prepBlocks, 256, 0, stream>>>(ei, hist, E, NB, nblk,
                                           x, xbf, n4, castBlocks,
                                           Wl1, Wr1, Wt1, Wl2, Wr2, Wt2);
    k_hscan<<<1, 1024, 0, stream>>>(hist, bbase, nblk, NB, E);
    k_scatter<<<nblk, 256, 0, stream>>>(ei, hist, pairs, E, NB);
    k_csr<<<NB, 256, 0, stream>>>(pairs, bbase, rowptr, eidx, n, E, NB);

    int aggBlocks = (n + 15) / 16;          // 16 nodes / block (4 waves x 4 nodes)
    int mmBlocks  = (n + 31) / 32;          // 32 rows / block

    // Layer 1: h = relu(mean_agg(xbf) @ Wl1 + b1 + xbf @ Wr1)
    k_aggb<<<aggBlocks, 256, 0, stream>>>(xbf, rowptr, eidx, aggbf, n);
    k_mm<<<mmBlocks, 512, 0, stream>>>(aggbf, xbf, Wt1, b1, hbf, n, 1, 1);
    // Layer 2: out = mean_agg(hbf) @ Wl2 + b2 + hbf @ Wr2
    k_aggb<<<aggBlocks, 256, 0, stream>>>(hbf, rowptr, eidx, aggbf, n);
    k_mm<<<mmBlocks, 512, 0, stream>>>(aggbf, hbf, Wt2, b2, out, n, 0, 0);
}

// Round 15
// 154.178 us; speedup vs baseline: 1.3469x; 1.0371x over previous
//
#include <hip/hip_runtime.h>
#include <hip/hip_bf16.h>

#define DD 128
#define BSH 8          // 256 nodes per bucket (CSR build)
#define CHUNK 4096     // edges per partition block

typedef __attribute__((ext_vector_type(8))) short short8v;
typedef __attribute__((ext_vector_type(4))) float f32x4;

static __device__ __forceinline__ ushort f2bf(float f) {
    __hip_bfloat16 b = __float2bfloat16(f);
    return *reinterpret_cast<ushort*>(&b);
}

// ---------------- merged prep: hist + cast + prepw1 + prepw2 ----------------

__global__ __launch_bounds__(256) void k_prep(const int* __restrict__ ei,
                                              int* __restrict__ hist, int E, int NB, int nblk,
                                              const float* __restrict__ x,
                                              ushort* __restrict__ xbf, int n4, int castBlocks,
                                              const float* __restrict__ Wl1,
                                              const float* __restrict__ Wr1,
                                              ushort* __restrict__ Wt1,
                                              const float* __restrict__ Wl2,
                                              const float* __restrict__ Wr2,
                                              ushort* __restrict__ Wt2) {
    __shared__ int lh[256];
    int t = threadIdx.x;
    int b = blockIdx.x;

    if (b < nblk) {
        lh[t] = 0;
        __syncthreads();
        int e0 = b * CHUNK;
        int e1 = min(e0 + CHUNK, E);
        for (int e = e0 + t; e < e1; e += 256)
            atomicAdd(&lh[ei[E + e] >> BSH], 1);
        __syncthreads();
        if (t < NB) hist[b * NB + t] = lh[t];
        return;
    }
    b -= nblk;
    if (b < castBlocks) {
        int i = b * 256 + t;
        if (i < n4) {
            float4 v = reinterpret_cast<const float4*>(x)[i];
            ushort4 o;
            o.x = f2bf(v.x); o.y = f2bf(v.y); o.z = f2bf(v.z); o.w = f2bf(v.w);
            reinterpret_cast<ushort4*>(xbf)[i] = o;
        }
        return;
    }
    b -= castBlocks;
    {
        const float* Wl = (b < 128) ? Wl1 : Wl2;
        const float* Wr = (b < 128) ? Wr1 : Wr2;
        ushort* Wt = (b < 128) ? Wt1 : Wt2;
        int idx = (b & 127) * 256 + t;   // 128*256 = 32768
        int nn = idx >> 8, k = idx & 255;
        float v = (k < 128) ? Wl[k * 128 + nn] : Wr[(k - 128) * 128 + nn];
        Wt[nn * 256 + k] = f2bf(v);
    }
}

__global__ __launch_bounds__(1024) void k_hscan(int* __restrict__ hist,
                                                int* __restrict__ bbase,
                                                int nblk, int NB, int E) {
    __shared__ int part[4][256];
    __shared__ int s[256];
    int t = threadIdx.x;
    int b = t & 255, g = t >> 8;
    int q = (nblk + 3) >> 2;
    int lo = g * q, hi = min(lo + q, nblk);
    int sum = 0;
    if (b < NB)
        for (int blk = lo; blk < hi; ++blk) sum += hist[blk * NB + b];
    part[g][b] = sum;
    __syncthreads();
    if (g == 0) s[b] = part[0][b] + part[1][b] + part[2][b] + part[3][b];
    __syncthreads();
    for (int off = 1; off < 256; off <<= 1) {
        int v = 0;
        if (g == 0 && b >= off) v = s[b - off];
        __syncthreads();
        if (g == 0) s[b] += v;
        __syncthreads();
    }
    int base = (b == 0) ? 0 : s[b - 1];
    if (g == 0 && b < NB) bbase[b] = base;
    if (t == 0) bbase[NB] = E;
    int run = base;
    for (int gg = 0; gg < g; ++gg) run += part[gg][b];
    if (b < NB)
        for (int blk = lo; blk < hi; ++blk) {
            int tmp = hist[blk * NB + b];
            hist[blk * NB + b] = run;
            run += tmp;
        }
}

__global__ __launch_bounds__(256) void k_scatter(const int* __restrict__ ei,
                                                 const int* __restrict__ hist,
                                                 uint* __restrict__ pairs, int E, int NB) {
    __shared__ int lofs[256];
    __shared__ int lh[256];
    int t = threadIdx.x;
    int blk = blockIdx.x;
    lh[t] = 0;
    if (t < NB) lofs[t] = hist[blk * NB + t];
    __syncthreads();
    int e0 = blk * CHUNK, e1 = min(e0 + CHUNK, E);
    for (int e = e0 + t; e < e1; e += 256) {
        int sN = ei[e];
        int d = ei[E + e];
        int b = d >> BSH;
        int lp = atomicAdd(&lh[b], 1);
        pairs[lofs[b] + lp] = ((uint)(d & 255) << 16) | (uint)sN;
    }
}

__global__ __launch_bounds__(256) void k_csr(const uint* __restrict__ pairs,
                                             const int* __restrict__ bbase,
                                             int* __restrict__ rowptr,
                                             ushort* __restrict__ eidx,
                                             int n, int E, int NB) {
    __shared__ int lc[256];
    __shared__ int cur[256];
    int t = threadIdx.x;
    int b = blockIdx.x;
    int node0 = b << BSH;
    lc[t] = 0;
    __syncthreads();
    int r0 = bbase[b], r1 = bbase[b + 1];
    for (int i = r0 + t; i < r1; i += 256)
        atomicAdd(&lc[pairs[i] >> 16], 1);
    __syncthreads();
    int c0 = lc[t];
#pragma unroll
    for (int off = 1; off < 256; off <<= 1) {
        int u = (t >= off) ? lc[t - off] : 0;
        __syncthreads();
        lc[t] += u;
        __syncthreads();
    }
    int rp = r0 + lc[t] - c0;
    int node = node0 + t;
    if (node < n) rowptr[node] = rp;
    if (b == NB - 1 && t == 0) rowptr[n] = E;
    cur[t] = rp;
    __syncthreads();
    for (int i = r0 + t; i < r1; i += 256) {
        uint pr = pairs[i];
        int p = atomicAdd(&cur[pr >> 16], 1);
        eidx[p] = (ushort)(pr & 0xFFFFu);
    }
}

// ---------------- fused SAGE layer v2: 32 nodes/block, 512 thr ----------------
// Phase A: stage root rows into sroot (coalesced, 1 chunk/thread).
// Phase B: 8 waves x 4 nodes (16-lane group per node), 8-row-deep gather
//   pipeline, fp32 acc, bf16 result into sagg.
// Phase C: wave wv = 16-col slice; 8 B-frags register-resident; A-frags from
//   LDS (agg half + root half); bias(+relu); store.
// LDS swizzle: 16B chunk c of row r stored at slot c^(r&15)  -> 2-way max on
// both the staging writes and the ds_read_b128 fragment reads.

#define ACC8(v)                                    \
    acc[0] += __uint_as_float((v).x << 16);        \
    acc[1] += __uint_as_float((v).x & 0xffff0000u);\
    acc[2] += __uint_as_float((v).y << 16);        \
    acc[3] += __uint_as_float((v).y & 0xffff0000u);\
    acc[4] += __uint_as_float((v).z << 16);        \
    acc[5] += __uint_as_float((v).z & 0xffff0000u);\
    acc[6] += __uint_as_float((v).w << 16);        \
    acc[7] += __uint_as_float((v).w & 0xffff0000u);

__global__ __launch_bounds__(512, 6) void k_fused(const ushort* __restrict__ hin,
                                                  const int* __restrict__ rowptr,
                                                  const ushort* __restrict__ eidx,
                                                  const ushort* __restrict__ Wt,
                                                  const float* __restrict__ bias,
                                                  void* __restrict__ outp,
                                                  int n, int relu, int outBf16) {
    __shared__ ushort sagg[32][128];    // 8 KB
    __shared__ ushort sroot[32][128];   // 8 KB

    int t = threadIdx.x;
    int node0 = blockIdx.x * 32;

    // ---- Phase A: stage root half (32 rows x 16 chunks, 1 chunk/thread) ----
    {
        int r = t >> 4, c = t & 15;
        int row = node0 + r;
        if (row >= n) row = n - 1;
        uint4 v = *reinterpret_cast<const uint4*>(hin + (size_t)row * DD + c * 8);
        int cs = c ^ (r & 15);
        *reinterpret_cast<uint4*>(&sroot[r][cs * 8]) = v;
    }

    // ---- Phase B: gather-aggregate, 4 nodes per wave ----
    int wave = t >> 6;
    int lane = t & 63;
    int grp = lane >> 4;
    int c16 = lane & 15;
    {
        int node = node0 + wave * 4 + grp;
        int beg = 0, end = 0;
        if (node < n) { beg = rowptr[node]; end = rowptr[node + 1]; }
        const uint4* base = reinterpret_cast<const uint4*>(hin);

        float acc[8];
#pragma unroll
        for (int i = 0; i < 8; ++i) acc[i] = 0.f;

        int e = beg;
        for (; e + 8 <= end; e += 8) {
            int id[8];
            uint4 v[8];
#pragma unroll
            for (int j = 0; j < 8; ++j) id[j] = eidx[e + j];
#pragma unroll
            for (int j = 0; j < 8; ++j) v[j] = base[(size_t)id[j] * 16 + c16];
#pragma unroll
            for (int j = 0; j < 8; ++j) { ACC8(v[j]); }
        }
        for (; e < end; e += 4) {
            int m = end - e;
            int i0 = eidx[e];
            int i1 = eidx[e + (m > 1 ? 1 : 0)];
            int i2 = eidx[e + (m > 2 ? 2 : 0)];
            int i3 = eidx[e + (m > 3 ? 3 : 0)];
            uint4 v0 = base[(size_t)i0 * 16 + c16];
            uint4 v1 = base[(size_t)i1 * 16 + c16];
            uint4 v2 = base[(size_t)i2 * 16 + c16];
            uint4 v3 = base[(size_t)i3 * 16 + c16];
            ACC8(v0);
            if (m > 1) { ACC8(v1); }
            if (m > 2) { ACC8(v2); }
            if (m > 3) { ACC8(v3); }
        }

        float inv = 1.0f / fmaxf((float)(end - beg), 1.0f);
        uint4 o;
        o.x = ((uint)f2bf(acc[1] * inv) << 16) | (uint)f2bf(acc[0] * inv);
        o.y = ((uint)f2bf(acc[3] * inv) << 16) | (uint)f2bf(acc[2] * inv);
        o.z = ((uint)f2bf(acc[5] * inv) << 16) | (uint)f2bf(acc[4] * inv);
        o.w = ((uint)f2bf(acc[7] * inv) << 16) | (uint)f2bf(acc[6] * inv);
        int r = wave * 4 + grp;
        int cs = c16 ^ (r & 15);
        *reinterpret_cast<uint4*>(&sagg[r][cs * 8]) = o;
    }
    __syncthreads();

    // ---- Phase C: MFMA GEMM for this block's 32 rows ----
    int lr = lane & 15;
    int lk = lane >> 4;
    int nt = wave;            // 16-col slice

    short8v bf[8];
    const ushort* wbase = Wt + (size_t)(nt * 16 + lr) * 256 + lk * 8;
#pragma unroll
    for (int ks = 0; ks < 8; ++ks)
        bf[ks] = *reinterpret_cast<const short8v*>(wbase + ks * 32);

    int col = nt * 16 + lr;
    float bv = bias[col];

#pragma unroll
    for (int sub = 0; sub < 2; ++sub) {
        int m0 = sub * 16;
        int r = m0 + lr;
        f32x4 acc = (f32x4){0.f, 0.f, 0.f, 0.f};
#pragma unroll
        for (int ks = 0; ks < 4; ++ks) {          // agg half (K = 0..127)
            int cc = ks * 4 + lk;
            int cs = cc ^ (r & 15);
            short8v af = *reinterpret_cast<const short8v*>(&sagg[r][cs * 8]);
            acc = __builtin_amdgcn_mfma_f32_16x16x32_bf16(af, bf[ks], acc, 0, 0, 0);
        }
#pragma unroll
        for (int ks = 0; ks < 4; ++ks) {          // root half (K = 128..255)
            int cc = ks * 4 + lk;
            int cs = cc ^ (r & 15);
            short8v af = *reinterpret_cast<const short8v*>(&sroot[r][cs * 8]);
            acc = __builtin_amdgcn_mfma_f32_16x16x32_bf16(af, bf[ks + 4], acc, 0, 0, 0);
        }

        int rowb = node0 + m0 + lk * 4;
#pragma unroll
        for (int q = 0; q < 4; ++q) {
            int row = rowb + q;
            if (row < n) {
                float v = acc[q] + bv;
                if (relu) v = fmaxf(v, 0.f);
                if (outBf16) {
                    reinterpret_cast<ushort*>(outp)[(size_t)row * DD + col] = f2bf(v);
                } else {
                    reinterpret_cast<float*>(outp)[(size_t)row * DD + col] = v;
                }
            }
        }
    }
}

// ---------------- launch ----------------

extern "C" void kernel_launch(void* const* d_in, const int* in_sizes, int n_in,
                              void* d_out, int out_size, void* d_ws, size_t ws_size,
                              hipStream_t stream) {
    const float* x   = (const float*)d_in[0];
    const int*   ei  = (const int*)d_in[1];
    const float* Wl1 = (const float*)d_in[2];
    const float* Wr1 = (const float*)d_in[3];
    const float* b1  = (const float*)d_in[4];
    const float* Wl2 = (const float*)d_in[5];
    const float* Wr2 = (const float*)d_in[6];
    const float* b2  = (const float*)d_in[7];
    float* out = (float*)d_out;

    int n = in_sizes[0] / DD;
    int E = in_sizes[1] / 2;

    int NB   = (n + 255) >> 8;          // buckets (<=256 for n<=65536)
    int nblk = (E + CHUNK - 1) / CHUNK; // partition chunks

    char* ws = (char*)d_ws;
    size_t off = 0;
    auto take = [&](size_t bytes) -> void* {
        void* p = ws + off;
        off = (off + bytes + 255) & ~(size_t)255;
        return p;
    };
    int* rowptr    = (int*)take(((size_t)n + 1) * 4);
    int* hist      = (int*)take((size_t)nblk * NB * 4);
    int* bbase     = (int*)take(((size_t)NB + 1) * 4);
    ushort* eidx   = (ushort*)take((size_t)E * 2 + 16);
    uint* pairs    = (uint*)take((size_t)E * 4);
    ushort* xbf    = (ushort*)take((size_t)n * DD * 2);
    ushort* hbf    = (ushort*)take((size_t)n * DD * 2);
    ushort* Wt1    = (ushort*)take((size_t)DD * 256 * 2);
    ushort* Wt2    = (ushort*)take((size_t)DD * 256 * 2);

    int n4 = n * DD / 4;
    int castBlocks = (n4 + 255) / 256;
    int prepBlocks = nblk + castBlocks + 256;

    k_prep<<<prepBlocks, 256, 0, stream>>>(ei, hist, E, NB, nblk,
                                           x, xbf, n4, castBlocks,
                                           Wl1, Wr1, Wt1, Wl2, Wr2, Wt2);
    k_hscan<<<1, 1024, 0, stream>>>(hist, bbase, nblk, NB, E);
    k_scatter<<<nblk, 256, 0, stream>>>(ei, hist, pairs, E, NB);
    k_csr<<<NB, 256, 0, stream>>>(pairs, bbase, rowptr, eidx, n, E, NB);

    int fusedBlocks = (n + 31) / 32;

    // Layer 1: hbf = relu(mean_agg(xbf) @ Wl1 + b1 + xbf @ Wr1)   [bf16 out]
    k_fused<<<fusedBlocks, 512, 0, stream>>>(xbf, rowptr, eidx, Wt1, b1, hbf, n, 1, 1);
    // Layer 2: out = mean_agg(hbf) @ Wl2 + b2 + hbf @ Wr2          [fp32 out]
    k_fused<<<fusedBlocks, 512, 0, stream>>>(hbf, rowptr, eidx, Wt2, b2, out, n, 0, 0);
}